// Round 13
// baseline (105.460 us; speedup 1.0000x reference)
//
#include <hip/hip_runtime.h>

// ModConv: y[b,o,p] = d[b,o] * sum_{c,tap} weight[o,c,tap] * style[b,c] * x[b,c,p+tap]
// Prologue (style, W2+wbf fused, d, border-zero, xspad) + bf16 MFMA implicit-GEMM conv.
// Conv: LDS-port-bound -> cut fragment-read traffic 25% with FAT wave tiles:
// 4 waves x (Mw=128, Nw=64) instead of 8 x (64,64). Round-6 loop structure
// (one barrier/K-tile, compiler lgkm waits, counted vmcnt) kept verbatim.

typedef __attribute__((ext_vector_type(8))) short bfx8;
typedef __attribute__((ext_vector_type(4))) float f32x4;
typedef __attribute__((ext_vector_type(4))) unsigned short us4;
typedef __attribute__((ext_vector_type(8))) unsigned short us8;

__device__ __forceinline__ unsigned short f2bf(float f) {
    unsigned int u = __builtin_bit_cast(unsigned int, f);
    u += 0x7FFFu + ((u >> 16) & 1u);          // round-to-nearest-even
    return (unsigned short)(u >> 16);
}

__device__ __forceinline__ void gload_lds16(const void* g, void* l) {
    __builtin_amdgcn_global_load_lds(
        (const __attribute__((address_space(1))) unsigned int*)g,
        (__attribute__((address_space(3))) unsigned int*)l,
        16, 0, 0);
}

__device__ __forceinline__ float wave_sum(float v) {
    #pragma unroll
    for (int m = 1; m < 64; m <<= 1) v += __shfl_xor(v, m, 64);
    return v;
}

__device__ __forceinline__ int shift_of(int t) {
    const int tap = t >> 3, q = t & 7;
    const int ky = tap / 3, kx = tap - ky * 3;
    return (ky * 34 + kx) * 512 + q * 64;
}

// ---------- prologue ----------

// style[b][c] = dot(w[b,:], affine_w[c,:]) + affine_b[c]; wave-per-output (8192 waves)
__global__ void style_kernel(const float* __restrict__ w,
                             const float* __restrict__ affine_w,
                             const float* __restrict__ affine_b,
                             float* __restrict__ style) {
    const int out = blockIdx.x * 4 + (threadIdx.x >> 6);
    const int lane = threadIdx.x & 63;
    const int b = out >> 9, c = out & 511;
    const float4 a0 = *(const float4*)(affine_w + (size_t)c * 512 + lane * 8);
    const float4 a1 = *(const float4*)(affine_w + (size_t)c * 512 + lane * 8 + 4);
    const float4 w0 = *(const float4*)(w + (size_t)b * 512 + lane * 8);
    const float4 w1 = *(const float4*)(w + (size_t)b * 512 + lane * 8 + 4);
    float acc = a0.x * w0.x + a0.y * w0.y + a0.z * w0.z + a0.w * w0.w
              + a1.x * w1.x + a1.y * w1.y + a1.z * w1.z + a1.w * w1.w;
    acc = wave_sum(acc);
    if (lane == 0) style[out] = acc + affine_b[c];
}

// Fused: W2[o][c] = sum_kk weight[o,c,:,:]^2  AND  wbf bf16 repack (swizzle baked).
// wbf[(t*8+q)][oc][64]: 16B sub-block s of row oc stored at position s ^ (oc&7).
__global__ void w2wbf_kernel(const float* __restrict__ weight,
                             float* __restrict__ W2,
                             unsigned short* __restrict__ wbf) {
    const int idx = blockIdx.x * 256 + threadIdx.x;   // 262144 = oc*512 + c
    const int oc = idx >> 9, c = idx & 511;
    const int q = c >> 6, c_local = c & 63;
    const int s = c_local >> 3, j = c_local & 7;
    const int pos = ((s ^ (oc & 7)) << 3) | j;
    const float* p = weight + (size_t)idx * 9;
    float ss = 0.f;
    #pragma unroll
    for (int t = 0; t < 9; ++t) {
        const float v = p[t];
        ss += v * v;
        wbf[((size_t)(t * 8 + q) * 512 + oc) * 64 + pos] = f2bf(v);
    }
    W2[idx] = ss;
}

// d[b][o] = rsqrt(sum_c style[b,c]^2 * W2[o,c] + eps); wave-per-output
__global__ void d_kernel(const float* __restrict__ style,
                         const float* __restrict__ W2,
                         float* __restrict__ dcoef) {
    const int out = blockIdx.x * 4 + (threadIdx.x >> 6);
    const int lane = threadIdx.x & 63;
    const int b = out >> 9, o = out & 511;
    const float4 s0 = *(const float4*)(style + (size_t)b * 512 + lane * 8);
    const float4 s1 = *(const float4*)(style + (size_t)b * 512 + lane * 8 + 4);
    const float4 v0 = *(const float4*)(W2 + (size_t)o * 512 + lane * 8);
    const float4 v1 = *(const float4*)(W2 + (size_t)o * 512 + lane * 8 + 4);
    float acc = s0.x * s0.x * v0.x + s0.y * s0.y * v0.y
              + s0.z * s0.z * v0.z + s0.w * s0.w * v0.w
              + s1.x * s1.x * v1.x + s1.y * s1.y * v1.y
              + s1.z * s1.z * v1.z + s1.w * s1.w * v1.w;
    acc = wave_sum(acc);
    if (lane == 0) dcoef[out] = rsqrtf(acc + 1e-8f);
}

// zero only the 132-cell pad border of xs[b][34][34][512]
__global__ void border_kernel(unsigned short* __restrict__ xs) {
    const int idx = blockIdx.x * 256 + threadIdx.x;   // 16*132*128 = 270336
    const int b = idx / (132 * 128);
    const int r_ = idx - b * (132 * 128);
    const int cell = r_ >> 7, t = r_ & 127;
    int rr, cc;
    if (cell < 34)      { rr = 0;  cc = cell; }
    else if (cell < 68) { rr = 33; cc = cell - 34; }
    else { const int jj = cell - 68; rr = 1 + (jj >> 1); cc = (jj & 1) ? 33 : 0; }
    us4 z = (us4){0, 0, 0, 0};
    *(us4*)(xs + (((size_t)b * 34 + rr) * 34 + cc) * 512 + t * 4) = z;
}

// xs_pad[b][34][34][512] bf16 (NHWC): interior [h+1][w+1][c] = x[b,c,h,w]*style[b,c]
__global__ void xspad_kernel(const float* __restrict__ x,
                             const float* __restrict__ style,
                             unsigned short* __restrict__ xs) {
    __shared__ __align__(16) unsigned short tile[128][36];
    const int b = blockIdx.z, h = blockIdx.y, c0 = blockIdx.x * 128;
    const int tid = threadIdx.x;               // 256
    #pragma unroll
    for (int it = 0; it < 4; ++it) {
        const int e = it * 256 + tid;
        const int ch = e >> 3, w4 = e & 7;
        const float4 v = *(const float4*)(x + (((size_t)b * 512 + c0 + ch) * 32 + h) * 32 + w4 * 4);
        const float sv = style[b * 512 + c0 + ch];
        us4 o;
        o.x = f2bf(v.x * sv); o.y = f2bf(v.y * sv);
        o.z = f2bf(v.z * sv); o.w = f2bf(v.w * sv);
        *(us4*)&tile[ch][w4 * 4] = o;
    }
    __syncthreads();
    #pragma unroll
    for (int it = 0; it < 2; ++it) {
        const int e = it * 256 + tid;
        const int cq = e & 15, w_ = e >> 4;
        us8 o;
        #pragma unroll
        for (int i = 0; i < 8; ++i) o[i] = tile[cq * 8 + i][w_];
        *(us8*)(xs + (((size_t)b * 34 + (h + 1)) * 34 + (w_ + 1)) * 512 + c0 + cq * 8) = o;
    }
}

// ---------- main conv ----------
// Implicit GEMM, BM=128(oc) x BN=256(px), BK=64, 72 K-tiles.
// 4 waves (256 thr), each wave: Mw=128 (all rows) x Nw=64 (col slice wv*64).
// 3-buffer LDS (48KB each: A 16KB + B 32KB), 2-tile-deep prefetch, vmcnt(12),
// one barrier per K-tile, XCD-bijective block remap.
#define LDS_RD(off) (*(const bfx8*)(lds + (off)))
#define MFMA(a, bb, c) __builtin_amdgcn_mfma_f32_16x16x32_bf16((a), (bb), (c), 0, 0, 0)

__global__ __launch_bounds__(256, 1) void conv_kernel(
    const unsigned short* __restrict__ wbf,
    const unsigned short* __restrict__ xs,
    const float* __restrict__ dcoef,
    float* __restrict__ out) {
    __shared__ __align__(16) char lds[147456];      // 3 x 49152 (A 16KB + B 32KB)

    // T1: XCD-bijective remap (256 = 8 XCD x 32). XCD k owns batches {2k,2k+1}.
    const int id = blockIdx.x;
    const int wid = (id & 7) * 32 + (id >> 3);
    const int b = wid >> 4;
    const int oc0 = ((wid >> 2) & 3) << 7;
    const int n0  = (wid & 3) << 8;

    const int tid = threadIdx.x;
    const int lane = tid & 63;
    const int wv = tid >> 6;            // 0..3
    const int l7 = lane & 7, l15 = lane & 15;

    // fragment-read constants
    const int swz0 = ((lane >> 4) ^ l7) << 4;          // ks=0
    const int swz1 = (((lane >> 4) + 4) ^ l7) << 4;    // ks=1
    const int arow = l15 * 128;                        // + mi*2048 + swz + buf
    const int brow = 16384 + (wv * 64 + l15) * 128;    // + ni*2048 + swz + buf

    // staging constants (wave-uniform LDS dst base; lane x 16B implicit)
    const int lsub = lane >> 3;                        // row-within-segment
    const int sx = l7 ^ lsub;                          // source sub-block swizzle (B only)
    // A: wave wv owns segments wv*4..wv*4+3 (rows wv*32 .. wv*32+31)
    int aoff[4];
    #pragma unroll
    for (int i = 0; i < 4; ++i) {
        const int ra = (wv * 4 + i) * 8 + lsub;
        aoff[i] = (oc0 + ra) * 64 + l7 * 8;            // wbf pre-swizzled -> linear l7
    }
    const int adst = (wv * 4) * 1024;                  // + i*1024
    // B: wave wv owns segments wv*8..wv*8+7 (pixel rows wv*64 .. wv*64+63)
    size_t bbase[8];
    const size_t xsb = (size_t)b * (34 * 34 * 512);
    #pragma unroll
    for (int i = 0; i < 8; ++i) {
        const int p = wv * 64 + i * 8 + lsub;          // pixel row 0..255
        const int n = n0 + p;
        bbase[i] = xsb + ((size_t)(n >> 5) * 34 + (n & 31)) * 512 + sx * 8;
    }
    const int bdst = 16384 + (wv * 8) * 1024;          // + i*1024

#define STAGE_ALL(tt, bo) do { \
        const unsigned short* wsrc_ = wbf + (size_t)(tt) * 32768; \
        const int sh_ = shift_of(tt); \
        _Pragma("unroll") \
        for (int i_ = 0; i_ < 4; ++i_) \
            gload_lds16(wsrc_ + aoff[i_], lds + (bo) + adst + i_ * 1024); \
        _Pragma("unroll") \
        for (int i_ = 0; i_ < 8; ++i_) \
            gload_lds16(xs + bbase[i_] + sh_, lds + (bo) + bdst + i_ * 1024); } while (0)

#define BARRIER() __builtin_amdgcn_s_barrier()

    f32x4 acc[8][4];
    #pragma unroll
    for (int i = 0; i < 8; ++i)
        #pragma unroll
        for (int j = 0; j < 4; ++j) acc[i][j] = (f32x4){0.f, 0.f, 0.f, 0.f};

    // prologue: stage tiles 0 and 1 (12 VMEM ops each)
    STAGE_ALL(0, 0);
    STAGE_ALL(1, 49152);
    asm volatile("s_waitcnt vmcnt(12)" ::: "memory");  // tile 0 landed
    BARRIER();

    int co = 0;
    #pragma unroll 1
    for (int t = 0; t < 72; ++t) {
        int so = co + 98304; if (so >= 147456) so -= 147456;   // buf for tile t+2
        const bool pf = (t < 70);

        bfx8 af0[8], bf0[4], af1[8], bf1[4];

        // all fragment reads for this tile (compiler inserts counted lgkm waits)
        #pragma unroll
        for (int mi = 0; mi < 8; ++mi) af0[mi] = LDS_RD(co + arow + mi * 2048 + swz0);
        #pragma unroll
        for (int ni = 0; ni < 4; ++ni) bf0[ni] = LDS_RD(co + brow + ni * 2048 + swz0);
        #pragma unroll
        for (int mi = 0; mi < 8; ++mi) af1[mi] = LDS_RD(co + arow + mi * 2048 + swz1);
        #pragma unroll
        for (int ni = 0; ni < 4; ++ni) bf1[ni] = LDS_RD(co + brow + ni * 2048 + swz1);

        // prefetch tile t+2 (stays in flight through the MFMAs)
        if (pf) STAGE_ALL(t + 2, so);

        __builtin_amdgcn_s_setprio(1);
        #pragma unroll
        for (int ni = 0; ni < 4; ++ni)
            #pragma unroll
            for (int mi = 0; mi < 8; ++mi)
                acc[mi][ni] = MFMA(af0[mi], bf0[ni], acc[mi][ni]);
        #pragma unroll
        for (int ni = 0; ni < 4; ++ni)
            #pragma unroll
            for (int mi = 0; mi < 8; ++mi)
                acc[mi][ni] = MFMA(af1[mi], bf1[ni], acc[mi][ni]);
        __builtin_amdgcn_s_setprio(0);

        // counted wait: 12 newest outstanding = tile t+2 -> tile t+1 fully landed.
        if (t < 70) { asm volatile("s_waitcnt vmcnt(12)" ::: "memory"); }
        else        { asm volatile("s_waitcnt vmcnt(0)"  ::: "memory"); }
        BARRIER();

        co += 49152; if (co >= 147456) co -= 147456;
    }

    // epilogue: scale by demod d[b][oc], write fp32 NCHW
    const int r4 = (lane >> 4) * 4;
    #pragma unroll
    for (int mi = 0; mi < 8; ++mi) {
        #pragma unroll
        for (int rr = 0; rr < 4; ++rr) {
            const int ocr = oc0 + mi * 16 + r4 + rr;
            const float dv = dcoef[b * 512 + ocr];
            float* orow = out + ((size_t)b * 512 + ocr) * 1024 + n0 + wv * 64 + l15;
            #pragma unroll
            for (int ni = 0; ni < 4; ++ni)
                orow[ni * 16] = acc[mi][ni][rr] * dv;
        }
    }
}

// ---------- launch ----------
extern "C" void kernel_launch(void* const* d_in, const int* in_sizes, int n_in,
                              void* d_out, int out_size, void* d_ws, size_t ws_size,
                              hipStream_t stream) {
    const float* x        = (const float*)d_in[0];   // (16,512,32,32)
    const float* w        = (const float*)d_in[1];   // (16,512)
    const float* weight   = (const float*)d_in[2];   // (512,512,3,3)
    const float* affine_w = (const float*)d_in[3];   // (512,512)
    const float* affine_b = (const float*)d_in[4];   // (512,)
    float* out = (float*)d_out;

    char* ws = (char*)d_ws;
    float*          style = (float*)(ws + 0);                 // 32 KB
    float*          W2    = (float*)(ws + 0x8000);            // 1 MB
    float*          dcoef = (float*)(ws + 0x108000);          // 32 KB
    unsigned short* wbf   = (unsigned short*)(ws + 0x110000); // 4.5 MB
    unsigned short* xs    = (unsigned short*)(ws + 0x590000); // 18.1 MB

    style_kernel<<<2048, 256, 0, stream>>>(w, affine_w, affine_b, style);
    w2wbf_kernel<<<1024, 256, 0, stream>>>(weight, W2, wbf);
    d_kernel<<<2048, 256, 0, stream>>>(style, W2, dcoef);
    border_kernel<<<1056, 256, 0, stream>>>(xs);
    xspad_kernel<<<dim3(4, 32, 16), 256, 0, stream>>>(x, style, xs);
    conv_kernel<<<256, 256, 0, stream>>>(wbf, xs, dcoef, out);
}

// Round 14
// 90.769 us; speedup vs baseline: 1.1619x; 1.1619x over previous
//
#include <hip/hip_runtime.h>

// ModConv: y[b,o,p] = d[b,o] * sum_{c,tap} weight[o,c,tap] * style[b,c] * x[b,c,p+tap]
// 3 kernels: K1 = style|w2wbf|border (fused by blockIdx range), K2 = d|xspad,
// K3 = conv (round-6 verified best: 3-buffer LDS, 1 barrier/K-tile, counted vmcnt).

typedef __attribute__((ext_vector_type(8))) short bfx8;
typedef __attribute__((ext_vector_type(4))) float f32x4;
typedef __attribute__((ext_vector_type(4))) unsigned short us4;
typedef __attribute__((ext_vector_type(8))) unsigned short us8;

__device__ __forceinline__ unsigned short f2bf(float f) {
    unsigned int u = __builtin_bit_cast(unsigned int, f);
    u += 0x7FFFu + ((u >> 16) & 1u);          // round-to-nearest-even
    return (unsigned short)(u >> 16);
}

__device__ __forceinline__ void gload_lds16(const void* g, void* l) {
    __builtin_amdgcn_global_load_lds(
        (const __attribute__((address_space(1))) unsigned int*)g,
        (__attribute__((address_space(3))) unsigned int*)l,
        16, 0, 0);
}

__device__ __forceinline__ float wave_sum(float v) {
    #pragma unroll
    for (int m = 1; m < 64; m <<= 1) v += __shfl_xor(v, m, 64);
    return v;
}

__device__ __forceinline__ int shift_of(int t) {
    const int tap = t >> 3, q = t & 7;
    const int ky = tap / 3, kx = tap - ky * 3;
    return (ky * 34 + kx) * 512 + q * 64;
}

// ---------- K1: style (2048) | w2wbf (1024) | border (1056) ----------
__global__ void pre1_kernel(const float* __restrict__ w,
                            const float* __restrict__ affine_w,
                            const float* __restrict__ affine_b,
                            const float* __restrict__ weight,
                            float* __restrict__ style,
                            float* __restrict__ W2,
                            unsigned short* __restrict__ wbf,
                            unsigned short* __restrict__ xs) {
    const int bid = blockIdx.x;
    const int tid = threadIdx.x;
    if (bid < 2048) {
        // style[b][c] = dot(w[b,:], affine_w[c,:]) + affine_b[c]; wave-per-output
        const int out = bid * 4 + (tid >> 6);
        const int lane = tid & 63;
        const int b = out >> 9, c = out & 511;
        const float4 a0 = *(const float4*)(affine_w + (size_t)c * 512 + lane * 8);
        const float4 a1 = *(const float4*)(affine_w + (size_t)c * 512 + lane * 8 + 4);
        const float4 w0 = *(const float4*)(w + (size_t)b * 512 + lane * 8);
        const float4 w1 = *(const float4*)(w + (size_t)b * 512 + lane * 8 + 4);
        float acc = a0.x * w0.x + a0.y * w0.y + a0.z * w0.z + a0.w * w0.w
                  + a1.x * w1.x + a1.y * w1.y + a1.z * w1.z + a1.w * w1.w;
        acc = wave_sum(acc);
        if (lane == 0) style[out] = acc + affine_b[c];
    } else if (bid < 3072) {
        // W2[o][c] = sum_kk weight^2 AND wbf bf16 repack (swizzle baked):
        // wbf[(t*8+q)][oc][64], 16B sub-block s of row oc at position s^(oc&7)
        const int idx = (bid - 2048) * 256 + tid;     // oc*512 + c
        const int oc = idx >> 9, c = idx & 511;
        const int q = c >> 6, c_local = c & 63;
        const int s = c_local >> 3, j = c_local & 7;
        const int pos = ((s ^ (oc & 7)) << 3) | j;
        const float* p = weight + (size_t)idx * 9;
        float ss = 0.f;
        #pragma unroll
        for (int t = 0; t < 9; ++t) {
            const float v = p[t];
            ss += v * v;
            wbf[((size_t)(t * 8 + q) * 512 + oc) * 64 + pos] = f2bf(v);
        }
        W2[idx] = ss;
    } else {
        // zero the 132-cell pad border of xs[b][34][34][512]
        const int idx = (bid - 3072) * 256 + tid;     // 16*132*128
        const int b = idx / (132 * 128);
        const int r_ = idx - b * (132 * 128);
        const int cell = r_ >> 7, t = r_ & 127;
        int rr, cc;
        if (cell < 34)      { rr = 0;  cc = cell; }
        else if (cell < 68) { rr = 33; cc = cell - 34; }
        else { const int jj = cell - 68; rr = 1 + (jj >> 1); cc = (jj & 1) ? 33 : 0; }
        us4 z = (us4){0, 0, 0, 0};
        *(us4*)(xs + (((size_t)b * 34 + rr) * 34 + cc) * 512 + t * 4) = z;
    }
}

// ---------- K2: d (2048) | xspad (2048) ----------
__global__ void pre2_kernel(const float* __restrict__ style,
                            const float* __restrict__ W2,
                            const float* __restrict__ x,
                            float* __restrict__ dcoef,
                            unsigned short* __restrict__ xs) {
    __shared__ __align__(16) unsigned short tile[128][36];
    const int bid = blockIdx.x;
    const int tid = threadIdx.x;
    if (bid < 2048) {
        // d[b][o] = rsqrt(sum_c style[b,c]^2 * W2[o,c] + eps); wave-per-output
        const int out = bid * 4 + (tid >> 6);
        const int lane = tid & 63;
        const int b = out >> 9, o = out & 511;
        const float4 s0 = *(const float4*)(style + (size_t)b * 512 + lane * 8);
        const float4 s1 = *(const float4*)(style + (size_t)b * 512 + lane * 8 + 4);
        const float4 v0 = *(const float4*)(W2 + (size_t)o * 512 + lane * 8);
        const float4 v1 = *(const float4*)(W2 + (size_t)o * 512 + lane * 8 + 4);
        float acc = s0.x * s0.x * v0.x + s0.y * s0.y * v0.y
                  + s0.z * s0.z * v0.z + s0.w * s0.w * v0.w
                  + s1.x * s1.x * v1.x + s1.y * s1.y * v1.y
                  + s1.z * s1.z * v1.z + s1.w * s1.w * v1.w;
        acc = wave_sum(acc);
        if (lane == 0) dcoef[out] = rsqrtf(acc + 1e-8f);
    } else {
        // xs[b][h+1][w+1][c] = bf16(x[b,c,h,w] * style[b,c])  (NHWC interior)
        const int e = bid - 2048;                     // 4 x 32 x 16
        const int c0 = (e & 3) * 128, h = (e >> 2) & 31, b = e >> 7;
        #pragma unroll
        for (int it = 0; it < 4; ++it) {
            const int ee = it * 256 + tid;
            const int ch = ee >> 3, w4 = ee & 7;
            const float4 v = *(const float4*)(x + (((size_t)b * 512 + c0 + ch) * 32 + h) * 32 + w4 * 4);
            const float sv = style[b * 512 + c0 + ch];
            us4 o;
            o.x = f2bf(v.x * sv); o.y = f2bf(v.y * sv);
            o.z = f2bf(v.z * sv); o.w = f2bf(v.w * sv);
            *(us4*)&tile[ch][w4 * 4] = o;
        }
        __syncthreads();
        #pragma unroll
        for (int it = 0; it < 2; ++it) {
            const int ee = it * 256 + tid;
            const int cq = ee & 15, w_ = ee >> 4;
            us8 o;
            #pragma unroll
            for (int i = 0; i < 8; ++i) o[i] = tile[cq * 8 + i][w_];
            *(us8*)(xs + (((size_t)b * 34 + (h + 1)) * 34 + (w_ + 1)) * 512 + c0 + cq * 8) = o;
        }
    }
}

// ---------- K3: conv (round-6 verified: 75.5 us) ----------
// Implicit GEMM, BM=128(oc) x BN=256(px), BK=64, 72 K-tiles, 8 waves (2M x 4N),
// 3-buffer LDS (48KB each: A 16KB + B 32KB), 2-tile-deep prefetch, vmcnt(6),
// ONE barrier per K-tile, XCD-bijective block remap.
#define LDS_RD(off) (*(const bfx8*)(lds + (off)))
#define MFMA(a, bb, c) __builtin_amdgcn_mfma_f32_16x16x32_bf16((a), (bb), (c), 0, 0, 0)

__global__ __launch_bounds__(512, 2) void conv_kernel(
    const unsigned short* __restrict__ wbf,
    const unsigned short* __restrict__ xs,
    const float* __restrict__ dcoef,
    float* __restrict__ out) {
    __shared__ __align__(16) char lds[147456];      // 3 x 49152 (A 16KB + B 32KB)

    // T1: XCD-bijective remap (256 = 8 XCD x 32). XCD k owns batches {2k,2k+1}.
    const int id = blockIdx.x;
    const int wid = (id & 7) * 32 + (id >> 3);
    const int b = wid >> 4;
    const int oc0 = ((wid >> 2) & 3) << 7;
    const int n0  = (wid & 3) << 8;

    const int tid = threadIdx.x;
    const int lane = tid & 63;
    const int wv = tid >> 6;            // 0..7
    const int wr = wv >> 2, wc = wv & 3;
    const int l7 = lane & 7, l15 = lane & 15;

    // fragment-read constants
    const int swz0 = ((lane >> 4) ^ l7) << 4;          // ks=0
    const int swz1 = (((lane >> 4) + 4) ^ l7) << 4;    // ks=1
    const int arow = (wr * 64 + l15) * 128;            // + mi*2048 + swz + buf
    const int brow = 16384 + (wc * 64 + l15) * 128;    // + ni*2048 + swz + buf

    // staging constants (wave-uniform LDS dst base; lane x 16B implicit)
    const int lsub = lane >> 3;                        // row-within-segment
    const int sx = l7 ^ lsub;                          // source sub-block swizzle (B only)
    const int ra0 = wv * 16 + lsub, ra1 = ra0 + 8;     // A rows
    // A: wbf is PRE-swizzled in memory -> linear l7 source sub-block
    const int aoff0 = (oc0 + ra0) * 64 + l7 * 8;
    const int aoff1 = (oc0 + ra1) * 64 + l7 * 8;
    const int adst0 = (wv * 2) * 1024, adst1 = adst0 + 1024;
    size_t bbase[4]; int bdst[4];
    const size_t xsb = (size_t)b * (34 * 34 * 512);
    #pragma unroll
    for (int i = 0; i < 4; ++i) {
        const int p = wv * 32 + i * 8 + lsub;          // pixel row 0..255
        const int n = n0 + p;
        bbase[i] = xsb + ((size_t)(n >> 5) * 34 + (n & 31)) * 512 + sx * 8;
        bdst[i] = 16384 + (wv * 4 + i) * 1024;
    }

#define STAGE_ALL(tt, bo) do { \
        const unsigned short* wsrc_ = wbf + (size_t)(tt) * 32768; \
        const int sh_ = shift_of(tt); \
        gload_lds16(wsrc_ + aoff0, lds + (bo) + adst0); \
        gload_lds16(wsrc_ + aoff1, lds + (bo) + adst1); \
        gload_lds16(xs + bbase[0] + sh_, lds + (bo) + bdst[0]); \
        gload_lds16(xs + bbase[1] + sh_, lds + (bo) + bdst[1]); \
        gload_lds16(xs + bbase[2] + sh_, lds + (bo) + bdst[2]); \
        gload_lds16(xs + bbase[3] + sh_, lds + (bo) + bdst[3]); } while (0)
#define BARRIER() __builtin_amdgcn_s_barrier()

    f32x4 acc[4][4];
    #pragma unroll
    for (int i = 0; i < 4; ++i)
        #pragma unroll
        for (int j = 0; j < 4; ++j) acc[i][j] = (f32x4){0.f, 0.f, 0.f, 0.f};

    // prologue: stage tiles 0 and 1
    STAGE_ALL(0, 0);
    STAGE_ALL(1, 49152);
    asm volatile("s_waitcnt vmcnt(6)" ::: "memory");   // tile 0 landed
    BARRIER();

    int co = 0;
    #pragma unroll 1
    for (int t = 0; t < 72; ++t) {
        int so = co + 98304; if (so >= 147456) so -= 147456;   // buf for tile t+2
        const bool pf = (t < 70);

        bfx8 af0[4], bf0[4], af1[4], bf1[4];

        // issue ALL fragment reads for this tile; compiler inserts counted
        // lgkm waits per consuming MFMA (no barrier between reads and MFMA).
        #pragma unroll
        for (int mi = 0; mi < 4; ++mi) af0[mi] = LDS_RD(co + arow + mi * 2048 + swz0);
        #pragma unroll
        for (int ni = 0; ni < 4; ++ni) bf0[ni] = LDS_RD(co + brow + ni * 2048 + swz0);
        #pragma unroll
        for (int mi = 0; mi < 4; ++mi) af1[mi] = LDS_RD(co + arow + mi * 2048 + swz1);
        #pragma unroll
        for (int ni = 0; ni < 4; ++ni) bf1[ni] = LDS_RD(co + brow + ni * 2048 + swz1);

        // issue prefetch for tile t+2 (lands under the MFMAs of t and t+1)
        if (pf) STAGE_ALL(t + 2, so);

        __builtin_amdgcn_s_setprio(1);
        #pragma unroll
        for (int ni = 0; ni < 4; ++ni)
            #pragma unroll
            for (int mi = 0; mi < 4; ++mi)
                acc[mi][ni] = MFMA(af0[mi], bf0[ni], acc[mi][ni]);
        #pragma unroll
        for (int ni = 0; ni < 4; ++ni)
            #pragma unroll
            for (int mi = 0; mi < 4; ++mi)
                acc[mi][ni] = MFMA(af1[mi], bf1[ni], acc[mi][ni]);
        __builtin_amdgcn_s_setprio(0);

        // counted wait: 6 newest outstanding = tile t+2 -> tile t+1 fully landed.
        if (t < 70) { asm volatile("s_waitcnt vmcnt(6)" ::: "memory"); }
        else        { asm volatile("s_waitcnt vmcnt(0)" ::: "memory"); }
        BARRIER();

        co += 49152; if (co >= 147456) co -= 147456;
    }

    // epilogue: scale by demod d[b][oc], write fp32 NCHW
    const int r4 = (lane >> 4) * 4;
    #pragma unroll
    for (int mi = 0; mi < 4; ++mi) {
        #pragma unroll
        for (int rr = 0; rr < 4; ++rr) {
            const int ocr = oc0 + wr * 64 + mi * 16 + r4 + rr;
            const float dv = dcoef[b * 512 + ocr];
            float* orow = out + ((size_t)b * 512 + ocr) * 1024 + n0 + wc * 64 + l15;
            #pragma unroll
            for (int ni = 0; ni < 4; ++ni)
                orow[ni * 16] = acc[mi][ni][rr] * dv;
        }
    }
}

// ---------- launch ----------
extern "C" void kernel_launch(void* const* d_in, const int* in_sizes, int n_in,
                              void* d_out, int out_size, void* d_ws, size_t ws_size,
                              hipStream_t stream) {
    const float* x        = (const float*)d_in[0];   // (16,512,32,32)
    const float* w        = (const float*)d_in[1];   // (16,512)
    const float* weight   = (const float*)d_in[2];   // (512,512,3,3)
    const float* affine_w = (const float*)d_in[3];   // (512,512)
    const float* affine_b = (const float*)d_in[4];   // (512,)
    float* out = (float*)d_out;

    char* ws = (char*)d_ws;
    float*          style = (float*)(ws + 0);                 // 32 KB
    float*          W2    = (float*)(ws + 0x8000);            // 1 MB
    float*          dcoef = (float*)(ws + 0x108000);          // 32 KB
    unsigned short* wbf   = (unsigned short*)(ws + 0x110000); // 4.5 MB
    unsigned short* xs    = (unsigned short*)(ws + 0x590000); // 18.1 MB

    pre1_kernel<<<4128, 256, 0, stream>>>(w, affine_w, affine_b, weight,
                                          style, W2, wbf, xs);
    pre2_kernel<<<4096, 256, 0, stream>>>(style, W2, x, dcoef, xs);
    conv_kernel<<<256, 512, 0, stream>>>(wbf, xs, dcoef, out);
}